// Round 27
// baseline (655.579 us; speedup 1.0000x reference)
//
#include <hip/hip_runtime.h>

#define B_ 16
#define N_ 1024
#define D_ 768
#define H_ 12
#define HD_ 64
// Q is pre-scaled by 0.125 * log2(e) so softmax is exp2-based.
#define QSCALE 0.18033688011112042f

typedef __attribute__((ext_vector_type(8))) __bf16 bf16x8;
typedef __attribute__((ext_vector_type(4))) float f32x4;
typedef unsigned short u16;
typedef unsigned int u32;

__device__ inline u16 f2bf(float f) {
    u32 u = __builtin_bit_cast(u32, f);
    u += 0x7fffu + ((u >> 16) & 1u);   // round-to-nearest-even
    return (u16)(u >> 16);
}

__device__ inline float fexp2(float x) {
#if __has_builtin(__builtin_amdgcn_exp2f)
    return __builtin_amdgcn_exp2f(x);
#else
    return exp2f(x);
#endif
}

__device__ inline u32 cvt_pk_bf16(float a, float b) {
    u32 r;
    asm("v_cvt_pk_bf16_f32 %0, %1, %2" : "=v"(r) : "v"(a), "v"(b));
    return r;
}

// async global->LDS, 16B per lane; LDS dest = wave-uniform base + lane*16
__device__ inline void gl_lds16(const u16* gp, u16* lp_) {
    __builtin_amdgcn_global_load_lds(
        (const __attribute__((address_space(1))) u32*)(gp),
        (__attribute__((address_space(3))) u32*)(lp_), 16, 0, 0);
}

// ---------------- kernel 1: prep = cvt_x + W transpose (merged) ----------
__global__ __launch_bounds__(256) void prep_kernel(
    const float* __restrict__ x, u16* __restrict__ xbf,
    const float* __restrict__ Wq, const float* __restrict__ Wk,
    const float* __restrict__ Wv, u16* __restrict__ wtall) {
    const int bid = blockIdx.x, tid = threadIdx.x;
    if (bid < 6144) {
        int i = bid * 256 + tid;
        const float4* p = (const float4*)x;
        float4 a = p[2 * i], b = p[2 * i + 1];
        union { u16 us[8]; int4 v; } u;
        u.us[0] = f2bf(a.x); u.us[1] = f2bf(a.y); u.us[2] = f2bf(a.z); u.us[3] = f2bf(a.w);
        u.us[4] = f2bf(b.x); u.us[5] = f2bf(b.y); u.us[6] = f2bf(b.z); u.us[7] = f2bf(b.w);
        ((int4*)xbf)[i] = u.v;
    } else {
        __shared__ u16 t[32][33];
        int wb = bid - 6144;                // 0..1727
        int z = wb / 576, rem = wb % 576;
        int bx = rem % 24, by = rem / 24;
        const float* W = z == 0 ? Wq : (z == 1 ? Wk : Wv);
        u16* Wt = wtall + (size_t)z * D_ * D_;
        int n0 = bx * 32, k0 = by * 32;
        int tx = tid & 31, ty = tid >> 5;   // 32 x 8
#pragma unroll
        for (int i = 0; i < 4; i++) {
            int k = k0 + ty + i * 8;
            t[ty + i * 8][tx] = f2bf(W[k * D_ + n0 + tx]);
        }
        __syncthreads();
#pragma unroll
        for (int i = 0; i < 4; i++) {
            int n = n0 + ty + i * 8;
            Wt[n * D_ + k0 + tx] = t[tx][ty + i * 8];
        }
    }
}

// ---------------- kernel 2: fused QKV GEMM (256x192, 2-slot ring) --------
// Geometry unchanged (BM=256, BN=192, 8 waves, BK=32 planes, both-sides
// swizzle: bank-conflict 0 verified). RING DEPTH 4 -> 2: LDS 128 -> 64 KB
// -> 2 blocks/CU (4 waves/SIMD) -> cross-block implicit overlap hides the
// phase bubbles (m97/m114 mechanism; previously 1 block/CU had nothing to
// hide under: 2900 cyc/phase vs 900 cyc MFMA). Uses the R12-proven
// race-free pattern: STAGE(cur^1, p+1) before COMPUTE(cur), __syncthreads
// per phase (prev barrier orders reads-before-overwrite; sync drains vm).
__global__ __launch_bounds__(512, 4) void qkv2_kernel(
    const u16* __restrict__ xbf, const u16* __restrict__ wtall,
    const float* __restrict__ bq, const float* __restrict__ bk, const float* __restrict__ bv,
    u16* __restrict__ qbf, u16* __restrict__ kbf, u16* __restrict__ vtbf) {
    __shared__ u16 lsA[2 * 8192];   // 2 slots x [256][32] bf16 = 32 KB
    __shared__ u16 lsB[2 * 8192];   // 2 slots x [256][32] bf16 = 32 KB

    const int mt = blockIdx.x, nt = blockIdx.y;
    const int tid = threadIdx.x, w = tid >> 6, lane = tid & 63;
    const int g = lane >> 4, c = lane & 15;
    const int wm = w >> 2, wn = w & 3;
    const int m0 = mt * 256, n0 = nt * 192;

    const int srow = w * 16 + (lane >> 2);
    const int gch = (lane & 3) ^ ((lane >> 3) & 3);
    const u16* sa0 = xbf + (size_t)(m0 + srow) * D_ + gch * 8;
    const u16* sa1 = xbf + (size_t)(m0 + 128 + srow) * D_ + gch * 8;
    const u16* sb0 = wtall + (size_t)(n0 + srow) * D_ + gch * 8;
    const u16* sb1 = wtall + (size_t)(n0 + 128 + srow) * D_ + gch * 8;

#define STAGEP(slot, p) do {                                          \
        gl_lds16(sa0 + (p) * 32, &lsA[(slot) * 8192 + w * 512]);        \
        gl_lds16(sa1 + (p) * 32, &lsA[(slot) * 8192 + 4096 + w * 512]); \
        gl_lds16(sb0 + (p) * 32, &lsB[(slot) * 8192 + w * 512]);        \
        gl_lds16(sb1 + (p) * 32, &lsB[(slot) * 8192 + 4096 + w * 512]); \
    } while (0)

    f32x4 acc[8][3];
#pragma unroll
    for (int i = 0; i < 8; i++)
#pragma unroll
        for (int j = 0; j < 3; j++) acc[i][j] = (f32x4){0.f, 0.f, 0.f, 0.f};

    const int gp8 = (g ^ ((c >> 1) & 3)) * 8;   // swizzled read chunk

#define COMPUTE(s) do {                                                         \
        bf16x8 af[8], bfr[3];                                                   \
        _Pragma("unroll")                                                       \
        for (int fr = 0; fr < 8; fr++)                                          \
            af[fr] = *(const bf16x8*)&lsA[(s) * 8192 + (wm * 128 + fr * 16 + c) * 32 + gp8]; \
        _Pragma("unroll")                                                       \
        for (int fc = 0; fc < 3; fc++)                                          \
            bfr[fc] = *(const bf16x8*)&lsB[(s) * 8192 + (wn * 48 + fc * 16 + c) * 32 + gp8]; \
        __builtin_amdgcn_s_setprio(1);                                          \
        _Pragma("unroll")                                                       \
        for (int fr = 0; fr < 8; fr++)                                          \
            _Pragma("unroll")                                                   \
            for (int fc = 0; fc < 3; fc++)                                      \
                acc[fr][fc] = __builtin_amdgcn_mfma_f32_16x16x32_bf16(          \
                    af[fr], bfr[fc], acc[fr][fc], 0, 0, 0);                     \
        __builtin_amdgcn_s_setprio(0);                                          \
    } while (0)

    STAGEP(0, 0);
    __syncthreads();               // slot0 ready (sync drains vmcnt)
    int cur = 0;
    for (int p = 0; p < 24; ++p) {          // 24 planes (768/32)
        if (p < 23) STAGEP(cur ^ 1, p + 1); // prefetch next plane
        COMPUTE(cur);
        __syncthreads();           // drains stage(p+1); orders reads vs overwrite
        cur ^= 1;
    }
#undef STAGEP
#undef COMPUTE

    const int mode = nt >> 2;              // 0=q 1=k 2=v  (4 nt per mode)
    const int msub = nt & 3;
    const float* bias = mode == 0 ? bq : (mode == 1 ? bk : bv);
    float bb[3];
#pragma unroll
    for (int fc = 0; fc < 3; fc++) bb[fc] = bias[msub * 192 + wn * 48 + fc * 16 + c];

    if (mode < 2) {
        u16* outp = mode == 0 ? qbf : kbf;
        const float osc = mode == 0 ? QSCALE : 1.0f;
#pragma unroll
        for (int fc = 0; fc < 3; fc++) {
            int col = msub * 192 + wn * 48 + fc * 16 + c;   // within-mode col
            int head = col >> 6, hd = col & 63;
#pragma unroll
            for (int fr = 0; fr < 8; fr++)
#pragma unroll
                for (int rr = 0; rr < 4; rr++) {
                    int m = m0 + wm * 128 + fr * 16 + g * 4 + rr;
                    int b = m >> 10, nn = m & 1023;
                    outp[(((size_t)b * H_ + head) * N_ + nn) * HD_ + hd] =
                        f2bf((acc[fr][fc][rr] + bb[fc]) * osc);
                }
        }
    } else {
#pragma unroll
        for (int fc = 0; fc < 3; fc++) {
            int col = msub * 192 + wn * 48 + fc * 16 + c;
            int head = col >> 6, hd = col & 63;
#pragma unroll
            for (int fr = 0; fr < 8; fr++) {
                int m = m0 + wm * 128 + fr * 16 + g * 4;
                int b = m >> 10, nn = m & 1023;
                union { u16 us[4]; int2 v; } u;
#pragma unroll
                for (int rr = 0; rr < 4; rr++) u.us[rr] = f2bf(acc[fr][fc][rr] + bb[fc]);
                *(int2*)&vtbf[(((size_t)b * H_ + head) * HD_ + hd) * N_ + nn] = u.v;
            }
        }
    }
}

// ---------------- kernel 3: flash attention (R24 + occupancy bound) ------
// R24 structure exactly; single change: __launch_bounds__(512, 6) caps
// VGPR at ~85 (was 88 — 3 over the 3-blocks/CU threshold 2048/24=85.3)
// -> 24 waves/CU instead of 16 (LDS 3 x 36.9 = 110.6 KB <= 160 OK).
__global__ __launch_bounds__(512, 6) void attn_kernel(
    const u16* __restrict__ qbf, const u16* __restrict__ kbf,
    const u16* __restrict__ vtbf, float* __restrict__ out) {
    __shared__ u16 lk[2][64][72];   // K tiles  [buf][kv][hd]
    __shared__ u16 lv[2][64][72];   // Vt tiles [buf][hd][kv]

    const int bh = blockIdx.x;      // 192 (x-major: same-bh blocks share XCD)
    const int qt = blockIdx.y;      // 4 q-tiles of 256
    const int b = bh / H_, h = bh % H_;
    const int tid = threadIdx.x;
    const int w = tid >> 6, lane = tid & 63, g = lane >> 4, c = lane & 15;
    const int q0 = qt * 256;

    bf16x8 aq[2][2];
#pragma unroll
    for (int ss = 0; ss < 2; ss++) {
        const u16* qr = qbf + ((size_t)bh * N_ + q0 + w * 32 + ss * 16 + c) * HD_;
        aq[ss][0] = *(const bf16x8*)&qr[g * 8];
        aq[ss][1] = *(const bf16x8*)&qr[32 + g * 8];
    }

    const u16* kbase = kbf + (size_t)bh * N_ * HD_;
    const u16* vbase = vtbf + (size_t)bh * HD_ * N_;
    const int r0 = tid >> 3, c80 = (tid & 7) * 8;   // 512 thr = 64 rows x 8 chunks

    int4 kreg0, vreg0;
#define LOADT(KV) do { \
        kreg0 = *(const int4*)(kbase + (size_t)((KV) + r0) * HD_ + c80); \
        vreg0 = *(const int4*)(vbase + (size_t)r0 * N_ + (KV) + c80); \
    } while (0)
#define WRITET(bi) do { \
        *(int4*)&lk[bi][r0][c80] = kreg0; \
        *(int4*)&lv[bi][r0][c80] = vreg0; \
    } while (0)

    const f32x4 zf = (f32x4){0.f, 0.f, 0.f, 0.f};   // persistent zero C-input
    f32x4 o[2][4];
#pragma unroll
    for (int ss = 0; ss < 2; ss++)
#pragma unroll
        for (int i = 0; i < 4; i++) o[ss][i] = zf;
    float lr[2] = {0.f, 0.f};       // per-lane PARTIAL row-sums

    LOADT(0);
    WRITET(0);
    __syncthreads();
    int cur = 0;

    for (int kv0 = 0; kv0 < N_; kv0 += 64) {
        const bool more = (kv0 + 64) < N_;
        if (more) LOADT(kv0 + 64);   // T14: latency hidden under this tile

        // S^T = K Q^T; sc[ss][nf]: kv = nf*16+g*4+r, q = w*32+ss*16+c
        f32x4 sc[2][4];
#pragma unroll
        for (int nf = 0; nf < 4; nf++) {
            bf16x8 ak0 = *(const bf16x8*)&lk[cur][nf * 16 + c][g * 8];
            bf16x8 ak1 = *(const bf16x8*)&lk[cur][nf * 16 + c][32 + g * 8];
            __builtin_amdgcn_s_setprio(1);
#pragma unroll
            for (int ss = 0; ss < 2; ss++) {
                sc[ss][nf] = __builtin_amdgcn_mfma_f32_16x16x32_bf16(ak0, aq[ss][0], zf, 0, 0, 0);
                sc[ss][nf] = __builtin_amdgcn_mfma_f32_16x16x32_bf16(ak1, aq[ss][1], sc[ss][nf], 0, 0, 0);
            }
            __builtin_amdgcn_s_setprio(0);
        }

        // P = exp2(S) directly (no max subtraction); per-lane partial sum;
        // pack to bf16 pairs (own-lane only)
        u32 pkk[2][4][2];
#pragma unroll
        for (int ss = 0; ss < 2; ss++) {
            f32x4 rsv = zf;
#pragma unroll
            for (int nf = 0; nf < 4; nf++) {
#pragma unroll
                for (int r = 0; r < 4; r++) sc[ss][nf][r] = fexp2(sc[ss][nf][r]);
                rsv += sc[ss][nf];
                pkk[ss][nf][0] = cvt_pk_bf16(sc[ss][nf][0], sc[ss][nf][1]);
                pkk[ss][nf][1] = cvt_pk_bf16(sc[ss][nf][2], sc[ss][nf][3]);
            }
            lr[ss] += (rsv[0] + rsv[1]) + (rsv[2] + rsv[3]);   // NO shuffles
        }

        // A-fragments from own registers (permuted k-slots)
        bf16x8 pa[2][2];
#pragma unroll
        for (int ss = 0; ss < 2; ss++) {
            union { u32 ui[4]; bf16x8 v; } u0, u1;
            u0.ui[0] = pkk[ss][0][0]; u0.ui[1] = pkk[ss][0][1];
            u0.ui[2] = pkk[ss][1][0]; u0.ui[3] = pkk[ss][1][1];
            u1.ui[0] = pkk[ss][2][0]; u1.ui[1] = pkk[ss][2][1];
            u1.ui[2] = pkk[ss][3][0]; u1.ui[3] = pkk[ss][3][1];
            pa[ss][0] = u0.v; pa[ss][1] = u1.v;
        }

        // PV: B-side reads lv columns in the SAME permuted kv order
#pragma unroll
        for (int nf = 0; nf < 4; nf++) {
            union { int2 d[2]; bf16x8 v; } b0, b1;
            b0.d[0] = *(const int2*)&lv[cur][nf * 16 + c][4 * g];
            b0.d[1] = *(const int2*)&lv[cur][nf * 16 + c][16 + 4 * g];
            b1.d[0] = *(const int2*)&lv[cur][nf * 16 + c][32 + 4 * g];
            b1.d[1] = *(const int2*)&lv[cur][nf * 16 + c][48 + 4 * g];
            __builtin_amdgcn_s_setprio(1);
#pragma unroll
            for (int ss = 0; ss < 2; ss++) {
                o[ss][nf] = __builtin_amdgcn_mfma_f32_16x16x32_bf16(pa[ss][0], b0.v, o[ss][nf], 0, 0, 0);
                o[ss][nf] = __builtin_amdgcn_mfma_f32_16x16x32_bf16(pa[ss][1], b1.v, o[ss][nf], 0, 0, 0);
            }
            __builtin_amdgcn_s_setprio(0);
        }

        if (more) WRITET(cur ^ 1);   // stage next tile into alternate buffer
        __syncthreads();             // single barrier per tile (dbuf)
        cur ^= 1;
    }
#undef LOADT
#undef WRITET

    // reduce lr partials once, then out[b, n, h*64+hd] = o / l
#pragma unroll
    for (int ss = 0; ss < 2; ss++) {
        float lf = lr[ss];
        lf += __shfl_xor(lf, 16);
        lf += __shfl_xor(lf, 32);
        float lq[4];
#pragma unroll
        for (int r = 0; r < 4; r++) lq[r] = __shfl(lf, g * 4 + r);
#pragma unroll
        for (int r = 0; r < 4; r++) {
            float inv = 1.f / lq[r];
            int n = q0 + w * 32 + ss * 16 + g * 4 + r;
#pragma unroll
            for (int nf = 0; nf < 4; nf++)
                out[((size_t)(b * N_ + n)) * D_ + h * HD_ + nf * 16 + c] = o[ss][nf][r] * inv;
        }
    }
}

// ---------------- launcher ----------------------------------------------
extern "C" void kernel_launch(void* const* d_in, const int* in_sizes, int n_in,
                              void* d_out, int out_size, void* d_ws, size_t ws_size,
                              hipStream_t stream) {
    const float* x  = (const float*)d_in[0];
    const float* Wq = (const float*)d_in[1];
    const float* bq = (const float*)d_in[2];
    const float* Wk = (const float*)d_in[3];
    const float* bk = (const float*)d_in[4];
    const float* Wv = (const float*)d_in[5];
    const float* bv = (const float*)d_in[6];
    float* out = (float*)d_out;

    char* ws = (char*)d_ws;
    u16* xbf   = (u16*)ws;                      // 16384*768*2 = 25165824 B
    u16* wtall = (u16*)(ws + 25165824);         // 2304*768*2  =  3538944 B
    u16* qbf   = (u16*)(ws + 28704768);         // [B,H,N,64] bf16 (prescaled)
    u16* kbf   = (u16*)(ws + 53870592);         // [B,H,N,64] bf16
    u16* vtbf  = (u16*)(ws + 79036416);         // [B,H,64,N] bf16

    prep_kernel<<<7872, 256, 0, stream>>>(x, xbf, Wq, Wk, Wv, wtall);
    dim3 gg(64, 12);    // mt-major: XCD = mt%8 -> A-tile readers share an XCD
    qkv2_kernel<<<gg, 512, 0, stream>>>(xbf, wtall, bq, bk, bv, qbf, kbf, vtbf);
    dim3 ga(192, 4);    // bh-major; 256 q-rows per block (8 waves)
    attn_kernel<<<ga, 512, 0, stream>>>(qbf, kbf, vtbf, out);
}

// Round 28
// 152.943 us; speedup vs baseline: 4.2864x; 4.2864x over previous
//
#include <hip/hip_runtime.h>

#define B_ 16
#define N_ 1024
#define D_ 768
#define H_ 12
#define HD_ 64
// Q is pre-scaled by 0.125 * log2(e) so softmax is exp2-based.
#define QSCALE 0.18033688011112042f

typedef __attribute__((ext_vector_type(8))) __bf16 bf16x8;
typedef __attribute__((ext_vector_type(4))) float f32x4;
typedef unsigned short u16;
typedef unsigned int u32;

__device__ inline u16 f2bf(float f) {
    u32 u = __builtin_bit_cast(u32, f);
    u += 0x7fffu + ((u >> 16) & 1u);   // round-to-nearest-even
    return (u16)(u >> 16);
}

__device__ inline float fexp2(float x) {
#if __has_builtin(__builtin_amdgcn_exp2f)
    return __builtin_amdgcn_exp2f(x);
#else
    return exp2f(x);
#endif
}

__device__ inline u32 cvt_pk_bf16(float a, float b) {
    u32 r;
    asm("v_cvt_pk_bf16_f32 %0, %1, %2" : "=v"(r) : "v"(a), "v"(b));
    return r;
}

// async global->LDS, 16B per lane; LDS dest = wave-uniform base + lane*16
__device__ inline void gl_lds16(const u16* gp, u16* lp_) {
    __builtin_amdgcn_global_load_lds(
        (const __attribute__((address_space(1))) u32*)(gp),
        (__attribute__((address_space(3))) u32*)(lp_), 16, 0, 0);
}

// ---------------- kernel 1: prep = cvt_x + W transpose (merged) ----------
__global__ __launch_bounds__(256) void prep_kernel(
    const float* __restrict__ x, u16* __restrict__ xbf,
    const float* __restrict__ Wq, const float* __restrict__ Wk,
    const float* __restrict__ Wv, u16* __restrict__ wtall) {
    const int bid = blockIdx.x, tid = threadIdx.x;
    if (bid < 6144) {
        int i = bid * 256 + tid;
        const float4* p = (const float4*)x;
        float4 a = p[2 * i], b = p[2 * i + 1];
        union { u16 us[8]; int4 v; } u;
        u.us[0] = f2bf(a.x); u.us[1] = f2bf(a.y); u.us[2] = f2bf(a.z); u.us[3] = f2bf(a.w);
        u.us[4] = f2bf(b.x); u.us[5] = f2bf(b.y); u.us[6] = f2bf(b.z); u.us[7] = f2bf(b.w);
        ((int4*)xbf)[i] = u.v;
    } else {
        __shared__ u16 t[32][33];
        int wb = bid - 6144;                // 0..1727
        int z = wb / 576, rem = wb % 576;
        int bx = rem % 24, by = rem / 24;
        const float* W = z == 0 ? Wq : (z == 1 ? Wk : Wv);
        u16* Wt = wtall + (size_t)z * D_ * D_;
        int n0 = bx * 32, k0 = by * 32;
        int tx = tid & 31, ty = tid >> 5;   // 32 x 8
#pragma unroll
        for (int i = 0; i < 4; i++) {
            int k = k0 + ty + i * 8;
            t[ty + i * 8][tx] = f2bf(W[k * D_ + n0 + tx]);
        }
        __syncthreads();
#pragma unroll
        for (int i = 0; i < 4; i++) {
            int n = n0 + ty + i * 8;
            Wt[n * D_ + k0 + tx] = t[tx][ty + i * 8];
        }
    }
}

// ---------------- kernel 2: fused QKV GEMM (256x192, 4-slot plane ring) --
// R17/R26 exact (measured best: ~85-90 us, bank-conflict 0). R27's 2-slot
// ring + (512,4) bound forced VGPR 88->64 (acc spilled to scratch) and cut
// prefetch distance: 336 us. REVERTED. VGPR floor here is the live acc
// (96 f32/lane) — min-waves launch bounds are a forbidden lever.
__global__ __launch_bounds__(512, 2) void qkv2_kernel(
    const u16* __restrict__ xbf, const u16* __restrict__ wtall,
    const float* __restrict__ bq, const float* __restrict__ bk, const float* __restrict__ bv,
    u16* __restrict__ qbf, u16* __restrict__ kbf, u16* __restrict__ vtbf) {
    __shared__ u16 lsA[4 * 8192];   // 4 slots x [256][32] bf16 = 64 KB
    __shared__ u16 lsB[4 * 8192];   // 4 slots x [256][32] bf16 = 64 KB

    const int mt = blockIdx.x, nt = blockIdx.y;
    const int tid = threadIdx.x, w = tid >> 6, lane = tid & 63;
    const int g = lane >> 4, c = lane & 15;
    const int wm = w >> 2, wn = w & 3;
    const int m0 = mt * 256, n0 = nt * 192;

    const int srow = w * 16 + (lane >> 2);
    const int gch = (lane & 3) ^ ((lane >> 3) & 3);
    const u16* sa0 = xbf + (size_t)(m0 + srow) * D_ + gch * 8;
    const u16* sa1 = xbf + (size_t)(m0 + 128 + srow) * D_ + gch * 8;
    const u16* sb0 = wtall + (size_t)(n0 + srow) * D_ + gch * 8;
    const u16* sb1 = wtall + (size_t)(n0 + 128 + srow) * D_ + gch * 8;

#define STAGEP(slot, p) do {                                          \
        gl_lds16(sa0 + (p) * 32, &lsA[(slot) * 8192 + w * 512]);        \
        gl_lds16(sa1 + (p) * 32, &lsA[(slot) * 8192 + 4096 + w * 512]); \
        gl_lds16(sb0 + (p) * 32, &lsB[(slot) * 8192 + w * 512]);        \
        gl_lds16(sb1 + (p) * 32, &lsB[(slot) * 8192 + 4096 + w * 512]); \
    } while (0)

    f32x4 acc[8][3];
#pragma unroll
    for (int i = 0; i < 8; i++)
#pragma unroll
        for (int j = 0; j < 3; j++) acc[i][j] = (f32x4){0.f, 0.f, 0.f, 0.f};

    const int gp8 = (g ^ ((c >> 1) & 3)) * 8;   // swizzled read chunk

#define COMPUTE(s) do {                                                         \
        bf16x8 af[8], bfr[3];                                                   \
        _Pragma("unroll")                                                       \
        for (int fr = 0; fr < 8; fr++)                                          \
            af[fr] = *(const bf16x8*)&lsA[(s) * 8192 + (wm * 128 + fr * 16 + c) * 32 + gp8]; \
        _Pragma("unroll")                                                       \
        for (int fc = 0; fc < 3; fc++)                                          \
            bfr[fc] = *(const bf16x8*)&lsB[(s) * 8192 + (wn * 48 + fc * 16 + c) * 32 + gp8]; \
        __builtin_amdgcn_s_setprio(1);                                          \
        _Pragma("unroll")                                                       \
        for (int fr = 0; fr < 8; fr++)                                          \
            _Pragma("unroll")                                                   \
            for (int fc = 0; fc < 3; fc++)                                      \
                acc[fr][fc] = __builtin_amdgcn_mfma_f32_16x16x32_bf16(          \
                    af[fr], bfr[fc], acc[fr][fc], 0, 0, 0);                     \
        __builtin_amdgcn_s_setprio(0);                                          \
    } while (0)

    STAGEP(0, 0);
    STAGEP(1, 1);
    for (int p = 0; p < 22; ++p) {          // 24 planes total (768/32)
        STAGEP((p + 2) & 3, p + 2);
        asm volatile("s_waitcnt vmcnt(8)" ::: "memory");   // plane p landed
        __builtin_amdgcn_s_barrier();
        __builtin_amdgcn_sched_barrier(0);
        COMPUTE(p & 3);
    }
    asm volatile("s_waitcnt vmcnt(4)" ::: "memory");       // plane 22 landed
    __builtin_amdgcn_s_barrier();
    __builtin_amdgcn_sched_barrier(0);
    COMPUTE(2);
    asm volatile("s_waitcnt vmcnt(0)" ::: "memory");       // plane 23 landed
    __builtin_amdgcn_s_barrier();
    __builtin_amdgcn_sched_barrier(0);
    COMPUTE(3);
#undef STAGEP
#undef COMPUTE

    const int mode = nt >> 2;              // 0=q 1=k 2=v  (4 nt per mode)
    const int msub = nt & 3;
    const float* bias = mode == 0 ? bq : (mode == 1 ? bk : bv);
    float bb[3];
#pragma unroll
    for (int fc = 0; fc < 3; fc++) bb[fc] = bias[msub * 192 + wn * 48 + fc * 16 + c];

    if (mode < 2) {
        u16* outp = mode == 0 ? qbf : kbf;
        const float osc = mode == 0 ? QSCALE : 1.0f;
#pragma unroll
        for (int fc = 0; fc < 3; fc++) {
            int col = msub * 192 + wn * 48 + fc * 16 + c;   // within-mode col
            int head = col >> 6, hd = col & 63;
#pragma unroll
            for (int fr = 0; fr < 8; fr++)
#pragma unroll
                for (int rr = 0; rr < 4; rr++) {
                    int m = m0 + wm * 128 + fr * 16 + g * 4 + rr;
                    int b = m >> 10, nn = m & 1023;
                    outp[(((size_t)b * H_ + head) * N_ + nn) * HD_ + hd] =
                        f2bf((acc[fr][fc][rr] + bb[fc]) * osc);
                }
        }
    } else {
#pragma unroll
        for (int fc = 0; fc < 3; fc++) {
            int col = msub * 192 + wn * 48 + fc * 16 + c;
            int head = col >> 6, hd = col & 63;
#pragma unroll
            for (int fr = 0; fr < 8; fr++) {
                int m = m0 + wm * 128 + fr * 16 + g * 4;
                int b = m >> 10, nn = m & 1023;
                union { u16 us[4]; int2 v; } u;
#pragma unroll
                for (int rr = 0; rr < 4; rr++) u.us[rr] = f2bf(acc[fr][fc][rr] + bb[fc]);
                *(int2*)&vtbf[(((size_t)b * H_ + head) * HD_ + hd) * N_ + nn] = u.v;
            }
        }
    }
}

// ---------------- kernel 3: flash attention (R24 exact) ------------------
// Measured best. 8 waves share each staged K/V tile (256 q-rows/block,
// grid 192x4), each thread stages ONE K-chunk + ONE V-chunk per tile.
// KVBLK=64, LDS dbuf (one barrier/tile). NO min-waves bound (R27's (512,6)
// forced VGPR 88->40: catastrophic spill, 979 MB scratch writes).
// Swapped QK^T, own-register PV A-fragments (permuted k-slots), no-max
// softmax, per-lane lr partials, T14 async-stage, bh-major grid, setprio.
__global__ __launch_bounds__(512) void attn_kernel(
    const u16* __restrict__ qbf, const u16* __restrict__ kbf,
    const u16* __restrict__ vtbf, float* __restrict__ out) {
    __shared__ u16 lk[2][64][72];   // K tiles  [buf][kv][hd]
    __shared__ u16 lv[2][64][72];   // Vt tiles [buf][hd][kv]

    const int bh = blockIdx.x;      // 192 (x-major: same-bh blocks share XCD)
    const int qt = blockIdx.y;      // 4 q-tiles of 256
    const int b = bh / H_, h = bh % H_;
    const int tid = threadIdx.x;
    const int w = tid >> 6, lane = tid & 63, g = lane >> 4, c = lane & 15;
    const int q0 = qt * 256;

    bf16x8 aq[2][2];
#pragma unroll
    for (int ss = 0; ss < 2; ss++) {
        const u16* qr = qbf + ((size_t)bh * N_ + q0 + w * 32 + ss * 16 + c) * HD_;
        aq[ss][0] = *(const bf16x8*)&qr[g * 8];
        aq[ss][1] = *(const bf16x8*)&qr[32 + g * 8];
    }

    const u16* kbase = kbf + (size_t)bh * N_ * HD_;
    const u16* vbase = vtbf + (size_t)bh * HD_ * N_;
    const int r0 = tid >> 3, c80 = (tid & 7) * 8;   // 512 thr = 64 rows x 8 chunks

    int4 kreg0, vreg0;
#define LOADT(KV) do { \
        kreg0 = *(const int4*)(kbase + (size_t)((KV) + r0) * HD_ + c80); \
        vreg0 = *(const int4*)(vbase + (size_t)r0 * N_ + (KV) + c80); \
    } while (0)
#define WRITET(bi) do { \
        *(int4*)&lk[bi][r0][c80] = kreg0; \
        *(int4*)&lv[bi][r0][c80] = vreg0; \
    } while (0)

    const f32x4 zf = (f32x4){0.f, 0.f, 0.f, 0.f};   // persistent zero C-input
    f32x4 o[2][4];
#pragma unroll
    for (int ss = 0; ss < 2; ss++)
#pragma unroll
        for (int i = 0; i < 4; i++) o[ss][i] = zf;
    float lr[2] = {0.f, 0.f};       // per-lane PARTIAL row-sums

    LOADT(0);
    WRITET(0);
    __syncthreads();
    int cur = 0;

    for (int kv0 = 0; kv0 < N_; kv0 += 64) {
        const bool more = (kv0 + 64) < N_;
        if (more) LOADT(kv0 + 64);   // T14: latency hidden under this tile

        // S^T = K Q^T; sc[ss][nf]: kv = nf*16+g*4+r, q = w*32+ss*16+c
        f32x4 sc[2][4];
#pragma unroll
        for (int nf = 0; nf < 4; nf++) {
            bf16x8 ak0 = *(const bf16x8*)&lk[cur][nf * 16 + c][g * 8];
            bf16x8 ak1 = *(const bf16x8*)&lk[cur][nf * 16 + c][32 + g * 8];
            __builtin_amdgcn_s_setprio(1);
#pragma unroll
            for (int ss = 0; ss < 2; ss++) {
                sc[ss][nf] = __builtin_amdgcn_mfma_f32_16x16x32_bf16(ak0, aq[ss][0], zf, 0, 0, 0);
                sc[ss][nf] = __builtin_amdgcn_mfma_f32_16x16x32_bf16(ak1, aq[ss][1], sc[ss][nf], 0, 0, 0);
            }
            __builtin_amdgcn_s_setprio(0);
        }

        // P = exp2(S) directly (no max subtraction); per-lane partial sum;
        // pack to bf16 pairs (own-lane only)
        u32 pkk[2][4][2];
#pragma unroll
        for (int ss = 0; ss < 2; ss++) {
            f32x4 rsv = zf;
#pragma unroll
            for (int nf = 0; nf < 4; nf++) {
#pragma unroll
                for (int r = 0; r < 4; r++) sc[ss][nf][r] = fexp2(sc[ss][nf][r]);
                rsv += sc[ss][nf];
                pkk[ss][nf][0] = cvt_pk_bf16(sc[ss][nf][0], sc[ss][nf][1]);
                pkk[ss][nf][1] = cvt_pk_bf16(sc[ss][nf][2], sc[ss][nf][3]);
            }
            lr[ss] += (rsv[0] + rsv[1]) + (rsv[2] + rsv[3]);   // NO shuffles
        }

        // A-fragments from own registers (permuted k-slots)
        bf16x8 pa[2][2];
#pragma unroll
        for (int ss = 0; ss < 2; ss++) {
            union { u32 ui[4]; bf16x8 v; } u0, u1;
            u0.ui[0] = pkk[ss][0][0]; u0.ui[1] = pkk[ss][0][1];
            u0.ui[2] = pkk[ss][1][0]; u0.ui[3] = pkk[ss][1][1];
            u1.ui[0] = pkk[ss][2][0]; u1.ui[1] = pkk[ss][2][1];
            u1.ui[2] = pkk[ss][3][0]; u1.ui[3] = pkk[ss][3][1];
            pa[ss][0] = u0.v; pa[ss][1] = u1.v;
        }

        // PV: B-side reads lv columns in the SAME permuted kv order
#pragma unroll
        for (int nf = 0; nf < 4; nf++) {
            union { int2 d[2]; bf16x8 v; } b0, b1;
            b0.d[0] = *(const int2*)&lv[cur][nf * 16 + c][4 * g];
            b0.d[1] = *(const int2*)&lv[cur][nf * 16 + c][16 + 4 * g];
            b1.d[0] = *(const int2*)&lv[cur][nf * 16 + c][32 + 4 * g];
            b1.d[1] = *(const int2*)&lv[cur][nf * 16 + c][48 + 4 * g];
            __builtin_amdgcn_s_setprio(1);
#pragma unroll
            for (int ss = 0; ss < 2; ss++) {
                o[ss][nf] = __builtin_amdgcn_mfma_f32_16x16x32_bf16(pa[ss][0], b0.v, o[ss][nf], 0, 0, 0);
                o[ss][nf] = __builtin_amdgcn_mfma_f32_16x16x32_bf16(pa[ss][1], b1.v, o[ss][nf], 0, 0, 0);
            }
            __builtin_amdgcn_s_setprio(0);
        }

        if (more) WRITET(cur ^ 1);   // stage next tile into alternate buffer
        __syncthreads();             // single barrier per tile (dbuf)
        cur ^= 1;
    }
#undef LOADT
#undef WRITET

    // reduce lr partials once, then out[b, n, h*64+hd] = o / l
#pragma unroll
    for (int ss = 0; ss < 2; ss++) {
        float lf = lr[ss];
        lf += __shfl_xor(lf, 16);
        lf += __shfl_xor(lf, 32);
        float lq[4];
#pragma unroll
        for (int r = 0; r < 4; r++) lq[r] = __shfl(lf, g * 4 + r);
#pragma unroll
        for (int r = 0; r < 4; r++) {
            float inv = 1.f / lq[r];
            int n = q0 + w * 32 + ss * 16 + g * 4 + r;
#pragma unroll
            for (int nf = 0; nf < 4; nf++)
                out[((size_t)(b * N_ + n)) * D_ + h * HD_ + nf * 16 + c] = o[ss][nf][r] * inv;
        }
    }
}

// ---------------- launcher ----------------------------------------------
extern "C" void kernel_launch(void* const* d_in, const int* in_sizes, int n_in,
                              void* d_out, int out_size, void* d_ws, size_t ws_size,
                              hipStream_t stream) {
    const float* x  = (const float*)d_in[0];
    const float* Wq = (const float*)d_in[1];
    const float* bq = (const float*)d_in[2];
    const float* Wk = (const float*)d_in[3];
    const float* bk = (const float*)d_in[4];
    const float* Wv = (const float*)d_in[5];
    const float* bv = (const float*)d_in[6];
    float* out = (float*)d_out;

    char* ws = (char*)d_ws;
    u16* xbf   = (u16*)ws;                      // 16384*768*2 = 25165824 B
    u16* wtall = (u16*)(ws + 25165824);         // 2304*768*2  =  3538944 B
    u16* qbf   = (u16*)(ws + 28704768);         // [B,H,N,64] bf16 (prescaled)
    u16* kbf   = (u16*)(ws + 53870592);         // [B,H,N,64] bf16
    u16* vtbf  = (u16*)(ws + 79036416);         // [B,H,64,N] bf16

    prep_kernel<<<7872, 256, 0, stream>>>(x, xbf, Wq, Wk, Wv, wtall);
    dim3 gg(64, 12);    // mt-major: XCD = mt%8 -> A-tile readers share an XCD
    qkv2_kernel<<<gg, 512, 0, stream>>>(xbf, wtall, bq, bk, bv, qbf, kbf, vtbf);
    dim3 ga(192, 4);    // bh-major; 256 q-rows per block (8 waves)
    attn_kernel<<<ga, 512, 0, stream>>>(qbf, kbf, vtbf, out);
}